// Round 1
// baseline (933.093 us; speedup 1.0000x reference)
//
#include <hip/hip_runtime.h>

#define NN 100000
#define NE 1600000
#define DD 128

constexpr int NP = 100096; // padded N for alignment

// ---- K1: weighted degree + integer count per destination ----
__global__ __launch_bounds__(256) void k_deg(const int* __restrict__ col,
    const float* __restrict__ ew, float* __restrict__ deg, int* __restrict__ cnt, int E) {
  for (int e = blockIdx.x * blockDim.x + threadIdx.x; e < E; e += gridDim.x * blockDim.x) {
    int c = col[e];
    atomicAdd(&deg[c], ew[e]);
    atomicAdd(&cnt[c], 1);
  }
}

// ---- K2: single-block scan of counts -> rowptr; dis = rsqrt(deg) ----
__global__ __launch_bounds__(1024) void k_scan(const float* __restrict__ deg,
    const int* __restrict__ cnt, float* __restrict__ dis, int* __restrict__ rowptr, int N) {
  __shared__ int ps[1024];
  int t = threadIdx.x;
  const int chunk = (N + 1023) / 1024;
  int beg = t * chunk;
  int end = min(beg + chunk, N);
  int s = 0;
  for (int i = beg; i < end; i++) s += cnt[i];
  ps[t] = s;
  __syncthreads();
  for (int off = 1; off < 1024; off <<= 1) {
    int v = (t >= off) ? ps[t - off] : 0;
    __syncthreads();
    ps[t] += v;
    __syncthreads();
  }
  int run = (t == 0) ? 0 : ps[t - 1];
  for (int i = beg; i < end; i++) {
    rowptr[i] = run;
    run += cnt[i];
    float d = deg[i];
    dis[i] = (d > 0.0f) ? rsqrtf(d) : 0.0f;
  }
  if (t == 1023) rowptr[N] = ps[1023];
}

// ---- K3: fill CSR (src index + fused norm weight) ----
__global__ __launch_bounds__(256) void k_fill(const int* __restrict__ row, const int* __restrict__ col,
    const float* __restrict__ ew, const float* __restrict__ dis, const int* __restrict__ rowptr,
    int* __restrict__ fillc, int* __restrict__ srcA, float* __restrict__ wnA, int E) {
  for (int e = blockIdx.x * blockDim.x + threadIdx.x; e < E; e += gridDim.x * blockDim.x) {
    int c = col[e], r = row[e];
    int pos = rowptr[c] + atomicAdd(&fillc[c], 1);
    srcA[pos] = r;
    wnA[pos] = dis[r] * ew[e] * dis[c];
  }
}

// ---- K4: dual GEMM: hl = x@Wl -> out, h = x@Wg -> ws ----
// block = 256 threads, 32 rows/block; thread t: rows (t>>4), (t>>4)+16, cols (t&15)*8..+7
__global__ __launch_bounds__(256) void k_gemm(const float* __restrict__ x,
    const float* __restrict__ Wl, const float* __restrict__ Wg,
    float* __restrict__ outHL, float* __restrict__ h, int N) {
  __shared__ float xs[32][129]; // +1 pad: conflict-free broadcast across 4 rows/wave
  int t = threadIdx.x;
  int rowbase = blockIdx.x * 32;
  for (int i = 0; i < 4; i++) {
    int idx = t + i * 256;        // float4 slot 0..1023
    int r = idx >> 5;             // 32 float4 per row
    int c4 = (idx & 31) * 4;
    int gr = rowbase + r;
    float4 v = make_float4(0.f, 0.f, 0.f, 0.f);
    if (gr < N) v = *(const float4*)&x[(size_t)gr * DD + c4];
    xs[r][c4 + 0] = v.x; xs[r][c4 + 1] = v.y; xs[r][c4 + 2] = v.z; xs[r][c4 + 3] = v.w;
  }
  __syncthreads();
  int d0 = (t & 15) * 8;
  int r0 = t >> 4;
  float accl0[8] = {}, accl1[8] = {}, accg0[8] = {}, accg1[8] = {};
  #pragma unroll 8
  for (int k = 0; k < DD; k++) {
    float x0 = xs[r0][k], x1 = xs[r0 + 16][k];
    float4 a = *(const float4*)&Wl[k * DD + d0];
    float4 b = *(const float4*)&Wl[k * DD + d0 + 4];
    float4 c = *(const float4*)&Wg[k * DD + d0];
    float4 d = *(const float4*)&Wg[k * DD + d0 + 4];
    float wl[8] = {a.x, a.y, a.z, a.w, b.x, b.y, b.z, b.w};
    float wg[8] = {c.x, c.y, c.z, c.w, d.x, d.y, d.z, d.w};
    #pragma unroll
    for (int j = 0; j < 8; j++) {
      accl0[j] += x0 * wl[j];
      accl1[j] += x1 * wl[j];
      accg0[j] += x0 * wg[j];
      accg1[j] += x1 * wg[j];
    }
  }
  int g0 = rowbase + r0, g1 = rowbase + r0 + 16;
  if (g0 < N) {
    *(float4*)&outHL[(size_t)g0 * DD + d0]     = make_float4(accl0[0], accl0[1], accl0[2], accl0[3]);
    *(float4*)&outHL[(size_t)g0 * DD + d0 + 4] = make_float4(accl0[4], accl0[5], accl0[6], accl0[7]);
    *(float4*)&h[(size_t)g0 * DD + d0]         = make_float4(accg0[0], accg0[1], accg0[2], accg0[3]);
    *(float4*)&h[(size_t)g0 * DD + d0 + 4]     = make_float4(accg0[4], accg0[5], accg0[6], accg0[7]);
  }
  if (g1 < N) {
    *(float4*)&outHL[(size_t)g1 * DD + d0]     = make_float4(accl1[0], accl1[1], accl1[2], accl1[3]);
    *(float4*)&outHL[(size_t)g1 * DD + d0 + 4] = make_float4(accl1[4], accl1[5], accl1[6], accl1[7]);
    *(float4*)&h[(size_t)g1 * DD + d0]         = make_float4(accg1[0], accg1[1], accg1[2], accg1[3]);
    *(float4*)&h[(size_t)g1 * DD + d0 + 4]     = make_float4(accg1[4], accg1[5], accg1[6], accg1[7]);
  }
}

// ---- K5: gather SpMM: out[dst] += sum_e wn[e] * h[src[e]]  (one wave per dst) ----
__global__ __launch_bounds__(256) void k_gather(const float* __restrict__ h,
    const int* __restrict__ rowptr, const int* __restrict__ srcA, const float* __restrict__ wnA,
    float* __restrict__ out, int N) {
  int wid = (blockIdx.x * blockDim.x + threadIdx.x) >> 6;
  int lane = threadIdx.x & 63;
  if (wid >= N) return;
  int beg = rowptr[wid], end = rowptr[wid + 1];
  float ax = 0.f, ay = 0.f;
  for (int e = beg; e < end; e++) {
    int s = srcA[e];
    float w = wnA[e];
    float2 hv = *(const float2*)&h[(size_t)s * DD + lane * 2];
    ax += w * hv.x;
    ay += w * hv.y;
  }
  float2 o = *(float2*)&out[(size_t)wid * DD + lane * 2];
  o.x += ax;
  o.y += ay;
  *(float2*)&out[(size_t)wid * DD + lane * 2] = o;
}

extern "C" void kernel_launch(void* const* d_in, const int* in_sizes, int n_in,
                              void* d_out, int out_size, void* d_ws, size_t ws_size,
                              hipStream_t stream) {
  const float* x  = (const float*)d_in[0];
  const int*   ei = (const int*)d_in[1];
  const float* ew = (const float*)d_in[2];
  const float* Wl = (const float*)d_in[3];
  const float* Wg = (const float*)d_in[4];
  float* out = (float*)d_out;
  const int N = NN, E = NE;
  const int* row = ei;      // src
  const int* col = ei + E;  // dst

  char* base = (char*)d_ws;
  float* deg   = (float*)(base);                       // NP f32   (zeroed)
  int*   cnt   = (int*)  (base + (size_t)NP * 4);      // NP i32   (zeroed)
  int*   fillc = (int*)  (base + (size_t)NP * 8);      // NP i32   (zeroed)
  float* dis   = (float*)(base + (size_t)NP * 12);     // NP f32
  int*   rowptr= (int*)  (base + (size_t)NP * 16);     // N+1 i32
  int*   srcA  = (int*)  (base + (size_t)NP * 20);     // E i32
  float* wnA   = (float*)(base + (size_t)NP * 20 + (size_t)E * 4); // E f32
  float* h     = (float*)(base + (size_t)NP * 20 + (size_t)E * 8); // N*DD f32

  hipMemsetAsync(base, 0, (size_t)NP * 12, stream); // deg, cnt, fillc

  k_deg<<<2048, 256, 0, stream>>>(col, ew, deg, cnt, E);
  k_scan<<<1, 1024, 0, stream>>>(deg, cnt, dis, rowptr, N);
  k_fill<<<2048, 256, 0, stream>>>(row, col, ew, dis, rowptr, fillc, srcA, wnA, E);
  k_gemm<<<(N + 31) / 32, 256, 0, stream>>>(x, Wl, Wg, out, h, N);
  k_gather<<<(N * 64 + 255) / 256, 256, 0, stream>>>(h, rowptr, srcA, wnA, out, N);
}

// Round 2
// 599.660 us; speedup vs baseline: 1.5560x; 1.5560x over previous
//
#include <hip/hip_runtime.h>

#define NN 100000
#define NE 1600000
#define DD 128

constexpr int NP = 100096; // padded N for alignment
constexpr int SCAN_BLKS = (NN + 255) / 256; // 391

// ---- K1: weighted degree + integer count per destination ----
__global__ __launch_bounds__(256) void k_deg(const int* __restrict__ col,
    const float* __restrict__ ew, float* __restrict__ deg, int* __restrict__ cnt, int E) {
  for (int e = blockIdx.x * blockDim.x + threadIdx.x; e < E; e += gridDim.x * blockDim.x) {
    int c = col[e];
    atomicAdd(&deg[c], ew[e]);
    atomicAdd(&cnt[c], 1);
  }
}

// ---- K2a: per-block partial sums of cnt ----
__global__ __launch_bounds__(256) void k_scan1(const int* __restrict__ cnt,
    int* __restrict__ bsum, int N) {
  int i = blockIdx.x * 256 + threadIdx.x;
  int v = (i < N) ? cnt[i] : 0;
  __shared__ int ws[4];
  #pragma unroll
  for (int off = 32; off >= 1; off >>= 1) v += __shfl_down(v, off, 64);
  if ((threadIdx.x & 63) == 0) ws[threadIdx.x >> 6] = v;
  __syncthreads();
  if (threadIdx.x == 0) bsum[blockIdx.x] = ws[0] + ws[1] + ws[2] + ws[3];
}

// ---- K2b: single-block scan of block sums -> exclusive block offsets ----
__global__ __launch_bounds__(512) void k_scan2(int* __restrict__ bsum, int B) {
  __shared__ int ps[512];
  int t = threadIdx.x;
  int v = (t < B) ? bsum[t] : 0;
  ps[t] = v;
  __syncthreads();
  for (int off = 1; off < 512; off <<= 1) {
    int u = (t >= off) ? ps[t - off] : 0;
    __syncthreads();
    ps[t] += u;
    __syncthreads();
  }
  if (t < B) bsum[t] = ps[t] - v; // exclusive
}

// ---- K2c: per-block exclusive scan + offset -> rowptr; dis = rsqrt(deg) ----
__global__ __launch_bounds__(256) void k_scan3(const float* __restrict__ deg,
    const int* __restrict__ cnt, const int* __restrict__ boff,
    float* __restrict__ dis, int* __restrict__ rowptr, int N) {
  __shared__ int ps[256];
  int i = blockIdx.x * 256 + threadIdx.x;
  int t = threadIdx.x;
  int v = (i < N) ? cnt[i] : 0;
  ps[t] = v;
  __syncthreads();
  for (int off = 1; off < 256; off <<= 1) {
    int u = (t >= off) ? ps[t - off] : 0;
    __syncthreads();
    ps[t] += u;
    __syncthreads();
  }
  if (i < N) {
    int excl = boff[blockIdx.x] + ps[t] - v;
    rowptr[i] = excl;
    if (i == N - 1) rowptr[N] = excl + v;
    float d = deg[i];
    dis[i] = (d > 0.0f) ? rsqrtf(d) : 0.0f;
  }
}

// ---- K3: fill CSR (src index + fused norm weight) ----
__global__ __launch_bounds__(256) void k_fill(const int* __restrict__ row, const int* __restrict__ col,
    const float* __restrict__ ew, const float* __restrict__ dis, const int* __restrict__ rowptr,
    int* __restrict__ fillc, int* __restrict__ srcA, float* __restrict__ wnA, int E) {
  for (int e = blockIdx.x * blockDim.x + threadIdx.x; e < E; e += gridDim.x * blockDim.x) {
    int c = col[e], r = row[e];
    int pos = rowptr[c] + atomicAdd(&fillc[c], 1);
    srcA[pos] = r;
    wnA[pos] = dis[r] * ew[e] * dis[c];
  }
}

// ---- K4: dual GEMM: hl = x@Wl -> out, h = x@Wg -> ws ----
__global__ __launch_bounds__(256) void k_gemm(const float* __restrict__ x,
    const float* __restrict__ Wl, const float* __restrict__ Wg,
    float* __restrict__ outHL, float* __restrict__ h, int N) {
  __shared__ float xs[32][129];
  int t = threadIdx.x;
  int rowbase = blockIdx.x * 32;
  for (int i = 0; i < 4; i++) {
    int idx = t + i * 256;
    int r = idx >> 5;
    int c4 = (idx & 31) * 4;
    int gr = rowbase + r;
    float4 v = make_float4(0.f, 0.f, 0.f, 0.f);
    if (gr < N) v = *(const float4*)&x[(size_t)gr * DD + c4];
    xs[r][c4 + 0] = v.x; xs[r][c4 + 1] = v.y; xs[r][c4 + 2] = v.z; xs[r][c4 + 3] = v.w;
  }
  __syncthreads();
  int d0 = (t & 15) * 8;
  int r0 = t >> 4;
  float accl0[8] = {}, accl1[8] = {}, accg0[8] = {}, accg1[8] = {};
  #pragma unroll 8
  for (int k = 0; k < DD; k++) {
    float x0 = xs[r0][k], x1 = xs[r0 + 16][k];
    float4 a = *(const float4*)&Wl[k * DD + d0];
    float4 b = *(const float4*)&Wl[k * DD + d0 + 4];
    float4 c = *(const float4*)&Wg[k * DD + d0];
    float4 d = *(const float4*)&Wg[k * DD + d0 + 4];
    float wl[8] = {a.x, a.y, a.z, a.w, b.x, b.y, b.z, b.w};
    float wg[8] = {c.x, c.y, c.z, c.w, d.x, d.y, d.z, d.w};
    #pragma unroll
    for (int j = 0; j < 8; j++) {
      accl0[j] += x0 * wl[j];
      accl1[j] += x1 * wl[j];
      accg0[j] += x0 * wg[j];
      accg1[j] += x1 * wg[j];
    }
  }
  int g0 = rowbase + r0, g1 = rowbase + r0 + 16;
  if (g0 < N) {
    *(float4*)&outHL[(size_t)g0 * DD + d0]     = make_float4(accl0[0], accl0[1], accl0[2], accl0[3]);
    *(float4*)&outHL[(size_t)g0 * DD + d0 + 4] = make_float4(accl0[4], accl0[5], accl0[6], accl0[7]);
    *(float4*)&h[(size_t)g0 * DD + d0]         = make_float4(accg0[0], accg0[1], accg0[2], accg0[3]);
    *(float4*)&h[(size_t)g0 * DD + d0 + 4]     = make_float4(accg0[4], accg0[5], accg0[6], accg0[7]);
  }
  if (g1 < N) {
    *(float4*)&outHL[(size_t)g1 * DD + d0]     = make_float4(accl1[0], accl1[1], accl1[2], accl1[3]);
    *(float4*)&outHL[(size_t)g1 * DD + d0 + 4] = make_float4(accl1[4], accl1[5], accl1[6], accl1[7]);
    *(float4*)&h[(size_t)g1 * DD + d0]         = make_float4(accg1[0], accg1[1], accg1[2], accg1[3]);
    *(float4*)&h[(size_t)g1 * DD + d0 + 4]     = make_float4(accg1[4], accg1[5], accg1[6], accg1[7]);
  }
}

// ---- K5: gather SpMM: out[dst] += sum_e wn[e] * h[src[e]]  (one wave per dst) ----
__global__ __launch_bounds__(256) void k_gather(const float* __restrict__ h,
    const int* __restrict__ rowptr, const int* __restrict__ srcA, const float* __restrict__ wnA,
    float* __restrict__ out, int N) {
  int wid = (blockIdx.x * blockDim.x + threadIdx.x) >> 6;
  int lane = threadIdx.x & 63;
  if (wid >= N) return;
  int beg = rowptr[wid], end = rowptr[wid + 1];
  float ax = 0.f, ay = 0.f;
  for (int e = beg; e < end; e++) {
    int s = srcA[e];
    float w = wnA[e];
    float2 hv = *(const float2*)&h[(size_t)s * DD + lane * 2];
    ax += w * hv.x;
    ay += w * hv.y;
  }
  float2 o = *(float2*)&out[(size_t)wid * DD + lane * 2];
  o.x += ax;
  o.y += ay;
  *(float2*)&out[(size_t)wid * DD + lane * 2] = o;
}

extern "C" void kernel_launch(void* const* d_in, const int* in_sizes, int n_in,
                              void* d_out, int out_size, void* d_ws, size_t ws_size,
                              hipStream_t stream) {
  const float* x  = (const float*)d_in[0];
  const int*   ei = (const int*)d_in[1];
  const float* ew = (const float*)d_in[2];
  const float* Wl = (const float*)d_in[3];
  const float* Wg = (const float*)d_in[4];
  float* out = (float*)d_out;
  const int N = NN, E = NE;
  const int* row = ei;      // src
  const int* col = ei + E;  // dst

  char* base = (char*)d_ws;
  float* deg   = (float*)(base);                       // NP f32   (zeroed)
  int*   cnt   = (int*)  (base + (size_t)NP * 4);      // NP i32   (zeroed)
  int*   fillc = (int*)  (base + (size_t)NP * 8);      // NP i32   (zeroed)
  float* dis   = (float*)(base + (size_t)NP * 12);     // NP f32
  int*   rowptr= (int*)  (base + (size_t)NP * 16);     // N+1 i32
  int*   bsum  = (int*)  (base + (size_t)NP * 16 + (size_t)(NP + 4) * 4); // SCAN_BLKS i32
  int*   srcA  = (int*)  (base + (size_t)NP * 20 + 4096);      // E i32
  float* wnA   = (float*)(base + (size_t)NP * 20 + 4096 + (size_t)E * 4); // E f32
  float* h     = (float*)(base + (size_t)NP * 20 + 4096 + (size_t)E * 8); // N*DD f32

  hipMemsetAsync(base, 0, (size_t)NP * 12, stream); // deg, cnt, fillc

  k_deg<<<2048, 256, 0, stream>>>(col, ew, deg, cnt, E);
  k_scan1<<<SCAN_BLKS, 256, 0, stream>>>(cnt, bsum, N);
  k_scan2<<<1, 512, 0, stream>>>(bsum, SCAN_BLKS);
  k_scan3<<<SCAN_BLKS, 256, 0, stream>>>(deg, cnt, bsum, dis, rowptr, N);
  k_fill<<<2048, 256, 0, stream>>>(row, col, ew, dis, rowptr, fillc, srcA, wnA, E);
  k_gemm<<<(N + 31) / 32, 256, 0, stream>>>(x, Wl, Wg, out, h, N);
  k_gather<<<(N * 64 + 255) / 256, 256, 0, stream>>>(h, rowptr, srcA, wnA, out, N);
}

// Round 3
// 431.466 us; speedup vs baseline: 2.1626x; 1.3898x over previous
//
#include <hip/hip_runtime.h>

#define NN 100000
#define NE 1600000
#define DD 128

constexpr int NP = 100096;
constexpr int SCAN_BLKS = (NN + 255) / 256; // 391

typedef __attribute__((ext_vector_type(8))) short bf16x8;
typedef __attribute__((ext_vector_type(4))) float f32x4;

__device__ inline unsigned short f2bf(float f) {
  union { float f; unsigned u; } v; v.f = f;
  unsigned r = (v.u + 0x7FFF + ((v.u >> 16) & 1)) >> 16;
  return (unsigned short)r;
}

// ---- K1: weighted degree + integer count per destination ----
__global__ __launch_bounds__(256) void k_deg(const int* __restrict__ col,
    const float* __restrict__ ew, float* __restrict__ deg, int* __restrict__ cnt, int E) {
  for (int e = blockIdx.x * blockDim.x + threadIdx.x; e < E; e += gridDim.x * blockDim.x) {
    int c = col[e];
    atomicAdd(&deg[c], ew[e]);
    atomicAdd(&cnt[c], 1);
  }
}

// ---- K2a/b/c: hierarchical scan ----
__global__ __launch_bounds__(256) void k_scan1(const int* __restrict__ cnt,
    int* __restrict__ bsum, int N) {
  int i = blockIdx.x * 256 + threadIdx.x;
  int v = (i < N) ? cnt[i] : 0;
  __shared__ int ws[4];
  #pragma unroll
  for (int off = 32; off >= 1; off >>= 1) v += __shfl_down(v, off, 64);
  if ((threadIdx.x & 63) == 0) ws[threadIdx.x >> 6] = v;
  __syncthreads();
  if (threadIdx.x == 0) bsum[blockIdx.x] = ws[0] + ws[1] + ws[2] + ws[3];
}

__global__ __launch_bounds__(512) void k_scan2(int* __restrict__ bsum, int B) {
  __shared__ int ps[512];
  int t = threadIdx.x;
  int v = (t < B) ? bsum[t] : 0;
  ps[t] = v;
  __syncthreads();
  for (int off = 1; off < 512; off <<= 1) {
    int u = (t >= off) ? ps[t - off] : 0;
    __syncthreads();
    ps[t] += u;
    __syncthreads();
  }
  if (t < B) bsum[t] = ps[t] - v;
}

__global__ __launch_bounds__(256) void k_scan3(const float* __restrict__ deg,
    const int* __restrict__ cnt, const int* __restrict__ boff,
    float* __restrict__ dis, int* __restrict__ rowptr, int N) {
  __shared__ int ps[256];
  int i = blockIdx.x * 256 + threadIdx.x;
  int t = threadIdx.x;
  int v = (i < N) ? cnt[i] : 0;
  ps[t] = v;
  __syncthreads();
  for (int off = 1; off < 256; off <<= 1) {
    int u = (t >= off) ? ps[t - off] : 0;
    __syncthreads();
    ps[t] += u;
    __syncthreads();
  }
  if (i < N) {
    int excl = boff[blockIdx.x] + ps[t] - v;
    rowptr[i] = excl;
    if (i == N - 1) rowptr[N] = excl + v;
    float d = deg[i];
    dis[i] = (d > 0.0f) ? rsqrtf(d) : 0.0f;
  }
}

// ---- K3: fill CSR ----
__global__ __launch_bounds__(256) void k_fill(const int* __restrict__ row, const int* __restrict__ col,
    const float* __restrict__ ew, const float* __restrict__ dis, const int* __restrict__ rowptr,
    int* __restrict__ fillc, int* __restrict__ srcA, float* __restrict__ wnA, int E) {
  for (int e = blockIdx.x * blockDim.x + threadIdx.x; e < E; e += gridDim.x * blockDim.x) {
    int c = col[e], r = row[e];
    int pos = rowptr[c] + atomicAdd(&fillc[c], 1);
    srcA[pos] = r;
    wnA[pos] = dis[r] * ew[e] * dis[c];
  }
}

// ---- K_wt: WT[n][k] = bf16(W[k][n]), n<128 -> Wl, else Wg ----
__global__ __launch_bounds__(64) void k_wt(const float* __restrict__ Wl,
    const float* __restrict__ Wg, unsigned short* __restrict__ WT) {
  int n = blockIdx.x; // 0..255
  const float* W = (n < DD) ? Wl : Wg;
  int c = n & (DD - 1);
  for (int k = threadIdx.x; k < DD; k += 64)
    WT[n * DD + k] = f2bf(W[k * DD + c]);
}

// ---- K4: MFMA dual GEMM: [hl | h] = x @ [Wl | Wg], bf16 inputs, f32 acc ----
// block: 256 thr = 4 waves; BM=64 rows; wave w owns output cols w*64..w*64+63 (of 256)
__global__ __launch_bounds__(256) void k_gemm(const float* __restrict__ x,
    const unsigned short* __restrict__ WT,
    float* __restrict__ outHL, float* __restrict__ h, int N) {
  __shared__ __align__(16) unsigned short Bl[256 * DD]; // 64KB, swizzled
  __shared__ __align__(16) unsigned short Al[64 * DD];  // 16KB, swizzled
  int t = threadIdx.x;
  int rowbase = blockIdx.x * 64;

  // stage B: 4096 x 16B chunks (row n: 128 bf16 = 16 chunks)
  const uint4* WTv = (const uint4*)WT;
  #pragma unroll
  for (int i = 0; i < 16; i++) {
    int ci = t + i * 256;           // 0..4095
    int n = ci >> 4, c16 = ci & 15;
    uint4 v = WTv[ci];
    int byte = (n << 8) + (c16 << 4);
    byte ^= (n & 7) << 4;
    *(uint4*)((char*)Bl + byte) = v;
  }
  // stage A: 64 rows x 128 f32 -> bf16 (2048 float4 chunks -> 8B LDS writes)
  #pragma unroll
  for (int i = 0; i < 8; i++) {
    int ci = t + i * 256;           // 0..2047
    int r = ci >> 5;
    int c4 = (ci & 31) * 4;
    int gr = rowbase + r;
    float4 v = make_float4(0.f, 0.f, 0.f, 0.f);
    if (gr < N) v = *(const float4*)&x[(size_t)gr * DD + c4];
    unsigned short b4[4] = {f2bf(v.x), f2bf(v.y), f2bf(v.z), f2bf(v.w)};
    int byte = r * 256 + c4 * 2;
    byte ^= (r & 7) << 4;
    *(uint2*)((char*)Al + byte) = *(uint2*)b4;
  }
  __syncthreads();

  int wid = t >> 6, lane = t & 63;
  int wn = wid * 64;                // wave col base in [0,256)
  int l15 = lane & 15, l4 = lane >> 4;
  f32x4 acc[4][4] = {};
  #pragma unroll
  for (int kk = 0; kk < 4; kk++) {
    bf16x8 af[4], bfr[4];
    #pragma unroll
    for (int m = 0; m < 4; m++) {
      int r = m * 16 + l15;
      int byte = r * 256 + kk * 64 + l4 * 16;
      byte ^= (r & 7) << 4;
      af[m] = *(const bf16x8*)((const char*)Al + byte);
    }
    #pragma unroll
    for (int n = 0; n < 4; n++) {
      int r = wn + n * 16 + l15;
      int byte = r * 256 + kk * 64 + l4 * 16;
      byte ^= (r & 7) << 4;
      bfr[n] = *(const bf16x8*)((const char*)Bl + byte);
    }
    #pragma unroll
    for (int m = 0; m < 4; m++)
      #pragma unroll
      for (int n = 0; n < 4; n++)
        acc[m][n] = __builtin_amdgcn_mfma_f32_16x16x32_bf16(af[m], bfr[n], acc[m][n], 0, 0, 0);
  }

  // store: D layout col=lane&15, row=(lane>>4)*4+j
  float* dst = (wn < DD) ? outHL : h;
  int cb = wn & (DD - 1);
  #pragma unroll
  for (int m = 0; m < 4; m++) {
    int gr0 = rowbase + m * 16 + l4 * 4;
    #pragma unroll
    for (int n = 0; n < 4; n++) {
      int gc = cb + n * 16 + l15;
      #pragma unroll
      for (int j = 0; j < 4; j++) {
        int gr = gr0 + j;
        if (gr < N) dst[(size_t)gr * DD + gc] = acc[m][n][j];
      }
    }
  }
}

// ---- K5: gather SpMM: out[dst] += sum_e wn[e] * h[src[e]] ----
__global__ __launch_bounds__(256) void k_gather(const float* __restrict__ h,
    const int* __restrict__ rowptr, const int* __restrict__ srcA, const float* __restrict__ wnA,
    float* __restrict__ out, int N) {
  int wid = (blockIdx.x * blockDim.x + threadIdx.x) >> 6;
  int lane = threadIdx.x & 63;
  if (wid >= N) return;
  int beg = rowptr[wid], end = rowptr[wid + 1];
  float ax = 0.f, ay = 0.f;
  for (int e = beg; e < end; e++) {
    int s = srcA[e];
    float w = wnA[e];
    float2 hv = *(const float2*)&h[(size_t)s * DD + lane * 2];
    ax += w * hv.x;
    ay += w * hv.y;
  }
  float2 o = *(float2*)&out[(size_t)wid * DD + lane * 2];
  o.x += ax;
  o.y += ay;
  *(float2*)&out[(size_t)wid * DD + lane * 2] = o;
}

extern "C" void kernel_launch(void* const* d_in, const int* in_sizes, int n_in,
                              void* d_out, int out_size, void* d_ws, size_t ws_size,
                              hipStream_t stream) {
  const float* x  = (const float*)d_in[0];
  const int*   ei = (const int*)d_in[1];
  const float* ew = (const float*)d_in[2];
  const float* Wl = (const float*)d_in[3];
  const float* Wg = (const float*)d_in[4];
  float* out = (float*)d_out;
  const int N = NN, E = NE;
  const int* row = ei;      // src
  const int* col = ei + E;  // dst

  char* base = (char*)d_ws;
  float* deg   = (float*)(base);
  int*   cnt   = (int*)  (base + (size_t)NP * 4);
  int*   fillc = (int*)  (base + (size_t)NP * 8);
  float* dis   = (float*)(base + (size_t)NP * 12);
  int*   rowptr= (int*)  (base + (size_t)NP * 16);
  int*   bsum  = (int*)  (base + (size_t)NP * 16 + (size_t)(NP + 4) * 4);
  int*   srcA  = (int*)  (base + (size_t)NP * 20 + 4096);
  float* wnA   = (float*)(base + (size_t)NP * 20 + 4096 + (size_t)E * 4);
  float* h     = (float*)(base + (size_t)NP * 20 + 4096 + (size_t)E * 8);
  unsigned short* WT = (unsigned short*)(h + (size_t)NN * DD); // 256*128 bf16

  hipMemsetAsync(base, 0, (size_t)NP * 12, stream); // deg, cnt, fillc

  k_deg<<<2048, 256, 0, stream>>>(col, ew, deg, cnt, E);
  k_wt<<<256, 64, 0, stream>>>(Wl, Wg, WT);
  k_scan1<<<SCAN_BLKS, 256, 0, stream>>>(cnt, bsum, N);
  k_scan2<<<1, 512, 0, stream>>>(bsum, SCAN_BLKS);
  k_scan3<<<SCAN_BLKS, 256, 0, stream>>>(deg, cnt, bsum, dis, rowptr, N);
  k_fill<<<2048, 256, 0, stream>>>(row, col, ew, dis, rowptr, fillc, srcA, wnA, E);
  k_gemm<<<(N + 63) / 64, 256, 0, stream>>>(x, WT, out, h, N);
  k_gather<<<(N * 64 + 255) / 256, 256, 0, stream>>>(h, rowptr, srcA, wnA, out, N);
}

// Round 4
// 370.872 us; speedup vs baseline: 2.5159x; 1.1634x over previous
//
#include <hip/hip_runtime.h>

#define NN 100000
#define NE 1600000
#define DD 128

constexpr int NP = 100096;
constexpr int SCAN_BLKS = (NN + 255) / 256; // 391

typedef __attribute__((ext_vector_type(8))) short bf16x8;
typedef __attribute__((ext_vector_type(4))) float f32x4;

__device__ inline unsigned short f2bf(float f) {
  union { float f; unsigned u; } v; v.f = f;
  unsigned r = (v.u + 0x7FFF + ((v.u >> 16) & 1)) >> 16;
  return (unsigned short)r;
}

// ---- K1: weighted degree + integer count per destination ----
__global__ __launch_bounds__(256) void k_deg(const int* __restrict__ col,
    const float* __restrict__ ew, float* __restrict__ deg, int* __restrict__ cnt, int E) {
  for (int e = blockIdx.x * blockDim.x + threadIdx.x; e < E; e += gridDim.x * blockDim.x) {
    int c = col[e];
    atomicAdd(&deg[c], ew[e]);
    atomicAdd(&cnt[c], 1);
  }
}

// ---- K2a/b/c: hierarchical scan ----
__global__ __launch_bounds__(256) void k_scan1(const int* __restrict__ cnt,
    int* __restrict__ bsum, int N) {
  int i = blockIdx.x * 256 + threadIdx.x;
  int v = (i < N) ? cnt[i] : 0;
  __shared__ int ws[4];
  #pragma unroll
  for (int off = 32; off >= 1; off >>= 1) v += __shfl_down(v, off, 64);
  if ((threadIdx.x & 63) == 0) ws[threadIdx.x >> 6] = v;
  __syncthreads();
  if (threadIdx.x == 0) bsum[blockIdx.x] = ws[0] + ws[1] + ws[2] + ws[3];
}

__global__ __launch_bounds__(512) void k_scan2(int* __restrict__ bsum, int B) {
  __shared__ int ps[512];
  int t = threadIdx.x;
  int v = (t < B) ? bsum[t] : 0;
  ps[t] = v;
  __syncthreads();
  for (int off = 1; off < 512; off <<= 1) {
    int u = (t >= off) ? ps[t - off] : 0;
    __syncthreads();
    ps[t] += u;
    __syncthreads();
  }
  if (t < B) bsum[t] = ps[t] - v;
}

__global__ __launch_bounds__(256) void k_scan3(const float* __restrict__ deg,
    const int* __restrict__ cnt, const int* __restrict__ boff,
    float* __restrict__ dis, int* __restrict__ rowptr, int N) {
  __shared__ int ps[256];
  int i = blockIdx.x * 256 + threadIdx.x;
  int t = threadIdx.x;
  int v = (i < N) ? cnt[i] : 0;
  ps[t] = v;
  __syncthreads();
  for (int off = 1; off < 256; off <<= 1) {
    int u = (t >= off) ? ps[t - off] : 0;
    __syncthreads();
    ps[t] += u;
    __syncthreads();
  }
  if (i < N) {
    int excl = boff[blockIdx.x] + ps[t] - v;
    rowptr[i] = excl;
    if (i == N - 1) rowptr[N] = excl + v;
    float d = deg[i];
    dis[i] = (d > 0.0f) ? rsqrtf(d) : 0.0f;
  }
}

// ---- K3: fill CSR ----
__global__ __launch_bounds__(256) void k_fill(const int* __restrict__ row, const int* __restrict__ col,
    const float* __restrict__ ew, const float* __restrict__ dis, const int* __restrict__ rowptr,
    int* __restrict__ fillc, int* __restrict__ srcA, float* __restrict__ wnA, int E) {
  for (int e = blockIdx.x * blockDim.x + threadIdx.x; e < E; e += gridDim.x * blockDim.x) {
    int c = col[e], r = row[e];
    int pos = rowptr[c] + atomicAdd(&fillc[c], 1);
    srcA[pos] = r;
    wnA[pos] = dis[r] * ew[e] * dis[c];
  }
}

// ---- K_wt: WT[n][k] = bf16(W[k][n]), n<128 -> Wl, else Wg ----
__global__ __launch_bounds__(64) void k_wt(const float* __restrict__ Wl,
    const float* __restrict__ Wg, unsigned short* __restrict__ WT) {
  int n = blockIdx.x; // 0..255
  const float* W = (n < DD) ? Wl : Wg;
  int c = n & (DD - 1);
  for (int k = threadIdx.x; k < DD; k += 64)
    WT[n * DD + k] = f2bf(W[k * DD + c]);
}

// ---- K4: MFMA dual GEMM: hl(f32)->out, h(bf16)->ws ----
__global__ __launch_bounds__(256) void k_gemm(const float* __restrict__ x,
    const unsigned short* __restrict__ WT,
    float* __restrict__ outHL, unsigned short* __restrict__ hb, int N) {
  __shared__ __align__(16) unsigned short Bl[256 * DD]; // 64KB, swizzled
  __shared__ __align__(16) unsigned short Al[64 * DD];  // 16KB, swizzled
  int t = threadIdx.x;
  int rowbase = blockIdx.x * 64;

  const uint4* WTv = (const uint4*)WT;
  #pragma unroll
  for (int i = 0; i < 16; i++) {
    int ci = t + i * 256;           // 0..4095
    int n = ci >> 4, c16 = ci & 15;
    uint4 v = WTv[ci];
    int byte = (n << 8) + (c16 << 4);
    byte ^= (n & 7) << 4;
    *(uint4*)((char*)Bl + byte) = v;
  }
  #pragma unroll
  for (int i = 0; i < 8; i++) {
    int ci = t + i * 256;           // 0..2047
    int r = ci >> 5;
    int c4 = (ci & 31) * 4;
    int gr = rowbase + r;
    float4 v = make_float4(0.f, 0.f, 0.f, 0.f);
    if (gr < N) v = *(const float4*)&x[(size_t)gr * DD + c4];
    unsigned short b4[4] = {f2bf(v.x), f2bf(v.y), f2bf(v.z), f2bf(v.w)};
    int byte = r * 256 + c4 * 2;
    byte ^= (r & 7) << 4;
    *(uint2*)((char*)Al + byte) = *(uint2*)b4;
  }
  __syncthreads();

  int wid = t >> 6, lane = t & 63;
  int wn = wid * 64;
  int l15 = lane & 15, l4 = lane >> 4;
  f32x4 acc[4][4] = {};
  #pragma unroll
  for (int kk = 0; kk < 4; kk++) {
    bf16x8 af[4], bfr[4];
    #pragma unroll
    for (int m = 0; m < 4; m++) {
      int r = m * 16 + l15;
      int byte = r * 256 + kk * 64 + l4 * 16;
      byte ^= (r & 7) << 4;
      af[m] = *(const bf16x8*)((const char*)Al + byte);
    }
    #pragma unroll
    for (int n = 0; n < 4; n++) {
      int r = wn + n * 16 + l15;
      int byte = r * 256 + kk * 64 + l4 * 16;
      byte ^= (r & 7) << 4;
      bfr[n] = *(const bf16x8*)((const char*)Bl + byte);
    }
    #pragma unroll
    for (int m = 0; m < 4; m++)
      #pragma unroll
      for (int n = 0; n < 4; n++)
        acc[m][n] = __builtin_amdgcn_mfma_f32_16x16x32_bf16(af[m], bfr[n], acc[m][n], 0, 0, 0);
  }

  // store: D layout col=lane&15, row=(lane>>4)*4+j
  int cb = wn & (DD - 1);
  if (wn < DD) {
    #pragma unroll
    for (int m = 0; m < 4; m++) {
      int gr0 = rowbase + m * 16 + l4 * 4;
      #pragma unroll
      for (int n = 0; n < 4; n++) {
        int gc = cb + n * 16 + l15;
        #pragma unroll
        for (int j = 0; j < 4; j++) {
          int gr = gr0 + j;
          if (gr < N) outHL[(size_t)gr * DD + gc] = acc[m][n][j];
        }
      }
    }
  } else {
    #pragma unroll
    for (int m = 0; m < 4; m++) {
      int gr0 = rowbase + m * 16 + l4 * 4;
      #pragma unroll
      for (int n = 0; n < 4; n++) {
        int gc = cb + n * 16 + l15;
        #pragma unroll
        for (int j = 0; j < 4; j++) {
          int gr = gr0 + j;
          if (gr < N) hb[(size_t)gr * DD + gc] = f2bf(acc[m][n][j]);
        }
      }
    }
  }
}

// ---- K5: gather SpMM on bf16 h: out[dst] += sum_e wn[e] * h[src[e]] ----
// one wave per dst; (src,wn) preloaded 64-wide, broadcast via shfl -> deep MLP
__global__ __launch_bounds__(256) void k_gather(const unsigned short* __restrict__ hb,
    const int* __restrict__ rowptr, const int* __restrict__ srcA, const float* __restrict__ wnA,
    float* __restrict__ out, int N) {
  int wid = (blockIdx.x * blockDim.x + threadIdx.x) >> 6;
  int lane = threadIdx.x & 63;
  if (wid >= N) return;
  int beg = rowptr[wid], end = rowptr[wid + 1];
  float ax = 0.f, ay = 0.f;
  for (int base = beg; base < end; base += 64) {
    int nv = min(64, end - base);
    int idx = base + lane;
    int s = 0; float w = 0.f;
    if (idx < end) { s = srcA[idx]; w = wnA[idx]; }
    for (int i = 0; i < nv; i++) {
      int si = __shfl(s, i, 64);
      float wi = __shfl(w, i, 64);
      unsigned hv = *(const unsigned*)&hb[(size_t)si * DD + lane * 2];
      union { unsigned u; float f; } lo, hi;
      lo.u = hv << 16;
      hi.u = hv & 0xFFFF0000u;
      ax += wi * lo.f;
      ay += wi * hi.f;
    }
  }
  float2 o = *(float2*)&out[(size_t)wid * DD + lane * 2];
  o.x += ax;
  o.y += ay;
  *(float2*)&out[(size_t)wid * DD + lane * 2] = o;
}

extern "C" void kernel_launch(void* const* d_in, const int* in_sizes, int n_in,
                              void* d_out, int out_size, void* d_ws, size_t ws_size,
                              hipStream_t stream) {
  const float* x  = (const float*)d_in[0];
  const int*   ei = (const int*)d_in[1];
  const float* ew = (const float*)d_in[2];
  const float* Wl = (const float*)d_in[3];
  const float* Wg = (const float*)d_in[4];
  float* out = (float*)d_out;
  const int N = NN, E = NE;
  const int* row = ei;      // src
  const int* col = ei + E;  // dst

  char* base = (char*)d_ws;
  float* deg   = (float*)(base);
  int*   cnt   = (int*)  (base + (size_t)NP * 4);
  int*   fillc = (int*)  (base + (size_t)NP * 8);
  float* dis   = (float*)(base + (size_t)NP * 12);
  int*   rowptr= (int*)  (base + (size_t)NP * 16);
  int*   bsum  = (int*)  (base + (size_t)NP * 16 + (size_t)(NP + 4) * 4);
  int*   srcA  = (int*)  (base + (size_t)NP * 20 + 4096);
  float* wnA   = (float*)(base + (size_t)NP * 20 + 4096 + (size_t)E * 4);
  unsigned short* hb = (unsigned short*)(base + (size_t)NP * 20 + 4096 + (size_t)E * 8); // N*DD bf16
  unsigned short* WT = hb + (size_t)NN * DD; // 256*128 bf16

  hipMemsetAsync(base, 0, (size_t)NP * 12, stream); // deg, cnt, fillc

  k_deg<<<2048, 256, 0, stream>>>(col, ew, deg, cnt, E);
  k_wt<<<256, 64, 0, stream>>>(Wl, Wg, WT);
  k_scan1<<<SCAN_BLKS, 256, 0, stream>>>(cnt, bsum, N);
  k_scan2<<<1, 512, 0, stream>>>(bsum, SCAN_BLKS);
  k_scan3<<<SCAN_BLKS, 256, 0, stream>>>(deg, cnt, bsum, dis, rowptr, N);
  k_fill<<<2048, 256, 0, stream>>>(row, col, ew, dis, rowptr, fillc, srcA, wnA, E);
  k_gemm<<<(N + 63) / 64, 256, 0, stream>>>(x, WT, out, hb, N);
  k_gather<<<(N * 64 + 255) / 256, 256, 0, stream>>>(hb, rowptr, srcA, wnA, out, N);
}

// Round 5
// 264.838 us; speedup vs baseline: 3.5233x; 1.4004x over previous
//
#include <hip/hip_runtime.h>

#define NN 100000
#define NE 1600000
#define DD 128

constexpr int NP = 100096;
constexpr int SCAN_BLKS = (NN + 255) / 256; // 391

typedef __attribute__((ext_vector_type(8))) short bf16x8;
typedef __attribute__((ext_vector_type(4))) float f32x4;

__device__ inline unsigned short f2bf(float f) {
  union { float f; unsigned u; } v; v.f = f;
  unsigned r = (v.u + 0x7FFF + ((v.u >> 16) & 1)) >> 16;
  return (unsigned short)r;
}

// ---- K1: packed degree+count atomic; returns per-edge CSR slot ----
// degcnt[c] = (count << 48) | sum(round(ew * 2^30))
__global__ __launch_bounds__(256) void k_deg(const int* __restrict__ col,
    const float* __restrict__ ew, unsigned long long* __restrict__ degcnt,
    int* __restrict__ epos, int E) {
  for (int e = blockIdx.x * blockDim.x + threadIdx.x; e < E; e += gridDim.x * blockDim.x) {
    int c = col[e];
    unsigned long long fx = (unsigned long long)(ew[e] * 1073741824.0f + 0.5f);
    unsigned long long old = atomicAdd(&degcnt[c], (1ULL << 48) | fx);
    epos[e] = (int)(old >> 48);
  }
}

// ---- K2a/b/c: hierarchical scan over packed counts ----
__global__ __launch_bounds__(256) void k_scan1(const unsigned long long* __restrict__ degcnt,
    int* __restrict__ bsum, int N) {
  int i = blockIdx.x * 256 + threadIdx.x;
  int v = (i < N) ? (int)(degcnt[i] >> 48) : 0;
  __shared__ int ws[4];
  #pragma unroll
  for (int off = 32; off >= 1; off >>= 1) v += __shfl_down(v, off, 64);
  if ((threadIdx.x & 63) == 0) ws[threadIdx.x >> 6] = v;
  __syncthreads();
  if (threadIdx.x == 0) bsum[blockIdx.x] = ws[0] + ws[1] + ws[2] + ws[3];
}

__global__ __launch_bounds__(512) void k_scan2(int* __restrict__ bsum, int B) {
  __shared__ int ps[512];
  int t = threadIdx.x;
  int v = (t < B) ? bsum[t] : 0;
  ps[t] = v;
  __syncthreads();
  for (int off = 1; off < 512; off <<= 1) {
    int u = (t >= off) ? ps[t - off] : 0;
    __syncthreads();
    ps[t] += u;
    __syncthreads();
  }
  if (t < B) bsum[t] = ps[t] - v;
}

__global__ __launch_bounds__(256) void k_scan3(const unsigned long long* __restrict__ degcnt,
    const int* __restrict__ boff, float* __restrict__ dis, int* __restrict__ rowptr, int N) {
  __shared__ int ps[256];
  int i = blockIdx.x * 256 + threadIdx.x;
  int t = threadIdx.x;
  unsigned long long v64 = (i < N) ? degcnt[i] : 0ULL;
  int v = (int)(v64 >> 48);
  ps[t] = v;
  __syncthreads();
  for (int off = 1; off < 256; off <<= 1) {
    int u = (t >= off) ? ps[t - off] : 0;
    __syncthreads();
    ps[t] += u;
    __syncthreads();
  }
  if (i < N) {
    int excl = boff[blockIdx.x] + ps[t] - v;
    rowptr[i] = excl;
    if (i == N - 1) rowptr[N] = excl + v;
    float d = (float)(v64 & 0xFFFFFFFFFFFFULL) * (1.0f / 1073741824.0f);
    dis[i] = (d > 0.0f) ? rsqrtf(d) : 0.0f;
  }
}

// ---- K3: fill CSR, atomic-free: edgeA[pos] = (wn_bits<<32) | src ----
__global__ __launch_bounds__(256) void k_fill(const int* __restrict__ row, const int* __restrict__ col,
    const float* __restrict__ ew, const float* __restrict__ dis, const int* __restrict__ rowptr,
    const int* __restrict__ epos, unsigned long long* __restrict__ edgeA, int E) {
  for (int e = blockIdx.x * blockDim.x + threadIdx.x; e < E; e += gridDim.x * blockDim.x) {
    int c = col[e], r = row[e];
    int pos = rowptr[c] + epos[e];
    float wn = dis[r] * ew[e] * dis[c];
    unsigned wb = __float_as_uint(wn);
    edgeA[pos] = ((unsigned long long)wb << 32) | (unsigned)r;
  }
}

// ---- K_wt: WT[n][k] = bf16(W[k][n]), n<128 -> Wl, else Wg ----
__global__ __launch_bounds__(64) void k_wt(const float* __restrict__ Wl,
    const float* __restrict__ Wg, unsigned short* __restrict__ WT) {
  int n = blockIdx.x; // 0..255
  const float* W = (n < DD) ? Wl : Wg;
  int c = n & (DD - 1);
  for (int k = threadIdx.x; k < DD; k += 64)
    WT[n * DD + k] = f2bf(W[k * DD + c]);
}

// ---- K4: MFMA dual GEMM: hl(f32)->out, h(bf16)->ws ----
__global__ __launch_bounds__(256) void k_gemm(const float* __restrict__ x,
    const unsigned short* __restrict__ WT,
    float* __restrict__ outHL, unsigned short* __restrict__ hb, int N) {
  __shared__ __align__(16) unsigned short Bl[256 * DD]; // 64KB, swizzled
  __shared__ __align__(16) unsigned short Al[64 * DD];  // 16KB, swizzled
  int t = threadIdx.x;
  int rowbase = blockIdx.x * 64;

  const uint4* WTv = (const uint4*)WT;
  #pragma unroll
  for (int i = 0; i < 16; i++) {
    int ci = t + i * 256;           // 0..4095
    int n = ci >> 4, c16 = ci & 15;
    uint4 v = WTv[ci];
    int byte = (n << 8) + (c16 << 4);
    byte ^= (n & 7) << 4;
    *(uint4*)((char*)Bl + byte) = v;
  }
  #pragma unroll
  for (int i = 0; i < 8; i++) {
    int ci = t + i * 256;           // 0..2047
    int r = ci >> 5;
    int c4 = (ci & 31) * 4;
    int gr = rowbase + r;
    float4 v = make_float4(0.f, 0.f, 0.f, 0.f);
    if (gr < N) v = *(const float4*)&x[(size_t)gr * DD + c4];
    unsigned short b4[4] = {f2bf(v.x), f2bf(v.y), f2bf(v.z), f2bf(v.w)};
    int byte = r * 256 + c4 * 2;
    byte ^= (r & 7) << 4;
    *(uint2*)((char*)Al + byte) = *(uint2*)b4;
  }
  __syncthreads();

  int wid = t >> 6, lane = t & 63;
  int wn = wid * 64;
  int l15 = lane & 15, l4 = lane >> 4;
  f32x4 acc[4][4] = {};
  #pragma unroll
  for (int kk = 0; kk < 4; kk++) {
    bf16x8 af[4], bfr[4];
    #pragma unroll
    for (int m = 0; m < 4; m++) {
      int r = m * 16 + l15;
      int byte = r * 256 + kk * 64 + l4 * 16;
      byte ^= (r & 7) << 4;
      af[m] = *(const bf16x8*)((const char*)Al + byte);
    }
    #pragma unroll
    for (int n = 0; n < 4; n++) {
      int r = wn + n * 16 + l15;
      int byte = r * 256 + kk * 64 + l4 * 16;
      byte ^= (r & 7) << 4;
      bfr[n] = *(const bf16x8*)((const char*)Bl + byte);
    }
    #pragma unroll
    for (int m = 0; m < 4; m++)
      #pragma unroll
      for (int n = 0; n < 4; n++)
        acc[m][n] = __builtin_amdgcn_mfma_f32_16x16x32_bf16(af[m], bfr[n], acc[m][n], 0, 0, 0);
  }

  int cb = wn & (DD - 1);
  if (wn < DD) {
    #pragma unroll
    for (int m = 0; m < 4; m++) {
      int gr0 = rowbase + m * 16 + l4 * 4;
      #pragma unroll
      for (int n = 0; n < 4; n++) {
        int gc = cb + n * 16 + l15;
        #pragma unroll
        for (int j = 0; j < 4; j++) {
          int gr = gr0 + j;
          if (gr < N) outHL[(size_t)gr * DD + gc] = acc[m][n][j];
        }
      }
    }
  } else {
    #pragma unroll
    for (int m = 0; m < 4; m++) {
      int gr0 = rowbase + m * 16 + l4 * 4;
      #pragma unroll
      for (int n = 0; n < 4; n++) {
        int gc = cb + n * 16 + l15;
        #pragma unroll
        for (int j = 0; j < 4; j++) {
          int gr = gr0 + j;
          if (gr < N) hb[(size_t)gr * DD + gc] = f2bf(acc[m][n][j]);
        }
      }
    }
  }
}

// ---- K5: gather SpMM on bf16 h with packed edges ----
__global__ __launch_bounds__(256) void k_gather(const unsigned short* __restrict__ hb,
    const int* __restrict__ rowptr, const unsigned long long* __restrict__ edgeA,
    float* __restrict__ out, int N) {
  int wid = (blockIdx.x * blockDim.x + threadIdx.x) >> 6;
  int lane = threadIdx.x & 63;
  if (wid >= N) return;
  int beg = rowptr[wid], end = rowptr[wid + 1];
  float ax = 0.f, ay = 0.f;
  for (int base = beg; base < end; base += 64) {
    int nv = min(64, end - base);
    int idx = base + lane;
    int s = 0, wb = 0;
    if (idx < end) {
      unsigned long long ev = edgeA[idx];
      s = (int)(unsigned)ev;
      wb = (int)(unsigned)(ev >> 32);
    }
    for (int i = 0; i < nv; i++) {
      int si = __shfl(s, i, 64);
      float wi = __uint_as_float((unsigned)__shfl(wb, i, 64));
      unsigned hv = *(const unsigned*)&hb[(size_t)si * DD + lane * 2];
      union { unsigned u; float f; } lo, hi;
      lo.u = hv << 16;
      hi.u = hv & 0xFFFF0000u;
      ax += wi * lo.f;
      ay += wi * hi.f;
    }
  }
  float2 o = *(float2*)&out[(size_t)wid * DD + lane * 2];
  o.x += ax;
  o.y += ay;
  *(float2*)&out[(size_t)wid * DD + lane * 2] = o;
}

extern "C" void kernel_launch(void* const* d_in, const int* in_sizes, int n_in,
                              void* d_out, int out_size, void* d_ws, size_t ws_size,
                              hipStream_t stream) {
  const float* x  = (const float*)d_in[0];
  const int*   ei = (const int*)d_in[1];
  const float* ew = (const float*)d_in[2];
  const float* Wl = (const float*)d_in[3];
  const float* Wg = (const float*)d_in[4];
  float* out = (float*)d_out;
  const int N = NN, E = NE;
  const int* row = ei;      // src
  const int* col = ei + E;  // dst

  char* base = (char*)d_ws;
  unsigned long long* degcnt = (unsigned long long*)base;            // NP u64 (zeroed)
  float* dis    = (float*)(base + (size_t)NP * 8);                   // NP f32
  int*   rowptr = (int*)  (base + (size_t)NP * 12);                  // N+1 i32
  int*   bsum   = (int*)  (base + (size_t)NP * 16 + 4096);           // SCAN_BLKS i32
  unsigned long long* edgeA = (unsigned long long*)(base + (size_t)NP * 16 + 8192); // E u64
  unsigned short* hb = (unsigned short*)((char*)edgeA + (size_t)NE * 8);            // N*DD bf16
  int* epos = (int*)hb;  // E i32, aliases hb (dead before k_gemm writes hb)
  unsigned short* WT = hb + (size_t)NN * DD;                         // 256*128 bf16

  hipMemsetAsync(base, 0, (size_t)NP * 8, stream); // degcnt

  k_deg<<<2048, 256, 0, stream>>>(col, ew, degcnt, epos, E);
  k_wt<<<256, 64, 0, stream>>>(Wl, Wg, WT);
  k_scan1<<<SCAN_BLKS, 256, 0, stream>>>(degcnt, bsum, N);
  k_scan2<<<1, 512, 0, stream>>>(bsum, SCAN_BLKS);
  k_scan3<<<SCAN_BLKS, 256, 0, stream>>>(degcnt, bsum, dis, rowptr, N);
  k_fill<<<2048, 256, 0, stream>>>(row, col, ew, dis, rowptr, epos, edgeA, E);
  k_gemm<<<(N + 63) / 64, 256, 0, stream>>>(x, WT, out, hb, N);
  k_gather<<<(N * 64 + 255) / 256, 256, 0, stream>>>(hb, rowptr, edgeA, out, N);
}